// Round 16
// baseline (65.232 us; speedup 1.0000x reference)
//
#include <hip/hip_runtime.h>
#include <math.h>

// MaxofErosions2D, pk-f16 pixel-pairs, PERSISTENT blocks + double-buffered LDS.
// out[b,h,w,f] = max_c min_{dy,dx} ( x[b,h+dy-2,w+dx-2,c] - kern[4-dy,4-dx,c,f] )
// x: (32,256,256,3) f32, kern: (5,5,3,8) f32, out: (32,256,256,8) f32.
//
// R16: attack the ~20us idle that survived conflicts/barriers/I$/occupancy
// experiments (R5..R15): the bulk-synchronous cohort structure serializes
// stage (mem-latency, VALU idle) and the 65.5MB store drain with compute.
// Fix: 512 persistent blocks x 4 consecutive 4-row tiles, LDS double-buffer:
//   issue loads(t+1) -> compute(t)+store(t) -> pack->lds[nxt] -> barrier.
// Inner math = R11 exactly (dup-k LDS broadcast, pk sub/min, alignbit pairs;
// busy floor 32us). dy loop rolled (2.3KB body; I$ exonerated by R15).

typedef _Float16 h2 __attribute__((ext_vector_type(2)));

static __device__ __forceinline__ h2 u2h(unsigned u) {
    return __builtin_bit_cast(h2, u);
}
static __device__ __forceinline__ unsigned packh(float a, float b) {
    return __builtin_bit_cast(unsigned, __builtin_amdgcn_cvt_pkrtz(a, b));
}

#define RST 132             // u32 pixel-pairs per plane row: cols -2..261
#define PST (8 * RST)       // 1056 u32 per channel plane (8 staged rows)
#define TILE_U (3 * PST)    // 3168 u32 = 12672 B per buffer
#define INF2 0x7C007C00u    // +inf f16 pair

__global__ __launch_bounds__(256) void maxero_pipe(
    const float* __restrict__ x,
    const float* __restrict__ kern,
    float* __restrict__ out)
{
    __shared__ __align__(16) unsigned xp[2][TILE_U];
    __shared__ __align__(16) unsigned kd[600];   // [tap][c][f] = {k,k} dup pairs

    const int tid = threadIdx.x;
    const int bI  = blockIdx.x;        // 512 blocks
    const int b   = bI >> 4;           // image 0..31
    const int seg = bI & 15;           // 16-row segment; tiles t: rows seg*16+4t..+3

    // ---- stage dup'd pre-flipped kernel (600 > 256: strided!)
    for (int i = tid; i < 600; i += 256) {
        int tap = i / 24, rem = i - tap * 24;
        int c = rem >> 3, f = rem & 7;
        int dy = tap / 5, dx = tap - dy * 5;
        float v = kern[((4 - dy) * 5 + (4 - dx)) * 24 + c * 8 + f];
        kd[i] = packh(v, v);
    }

    const float* xb = x + (size_t)b * (256 * 256 * 3);
    const int rr0 = tid >> 6;          // staging row (k=0: 0..3, k=1: +4)
    const int pg  = tid & 63;          // pixel group: cols 4pg..4pg+3
    const int hrow = rr0;              // compute row within tile (0..3)
    const int w0   = pg << 2;          // 0..252

    // ---- prologue: load+pack tile 0 into xp[0]
    float4 pv[6]; bool prv[2];
    #pragma unroll
    for (int k = 0; k < 2; ++k) {
        int r  = seg * 16 - 2 + rr0 + k * 4;
        prv[k] = (unsigned)r < 256u;
        int rc = min(max(r, 0), 255);
        const float4* gp = reinterpret_cast<const float4*>(xb + rc * 768 + pg * 12);
        pv[k*3+0] = gp[0]; pv[k*3+1] = gp[1]; pv[k*3+2] = gp[2];
    }
    #pragma unroll
    for (int k = 0; k < 2; ++k) {
        int base = (rr0 + k * 4) * RST + 2 * pg + 1;
        float4 v0 = pv[k*3], v1 = pv[k*3+1], v2 = pv[k*3+2];
        const float fv[12] = { v0.x,v0.y,v0.z,v0.w, v1.x,v1.y,v1.z,v1.w,
                               v2.x,v2.y,v2.z,v2.w };
        #pragma unroll
        for (int c = 0; c < 3; ++c) {
            xp[0][c*PST + base]     = prv[k] ? packh(fv[c],   fv[3+c]) : INF2;
            xp[0][c*PST + base + 1] = prv[k] ? packh(fv[6+c], fv[9+c]) : INF2;
        }
    }
    if (tid < 48) {
        int c = tid >> 4, rem = tid & 15, rr = rem >> 1, side = rem & 1;
        xp[0][c*PST + rr*RST + (side ? 129 : 0)] = INF2;
    }
    __syncthreads();

    // ---- pipelined tile loop
    #pragma unroll 1
    for (int t = 0; t < 4; ++t) {
        // issue next tile's global loads (hidden under this tile's compute)
        float4 nv[6]; bool nrv[2];
        if (t < 3) {
            #pragma unroll
            for (int k = 0; k < 2; ++k) {
                int r  = seg * 16 + (t + 1) * 4 - 2 + rr0 + k * 4;
                nrv[k] = (unsigned)r < 256u;
                int rc = min(max(r, 0), 255);
                const float4* gp = reinterpret_cast<const float4*>(xb + rc*768 + pg*12);
                nv[k*3+0] = gp[0]; nv[k*3+1] = gp[1]; nv[k*3+2] = gp[2];
            }
        }

        // ---- compute tile t from xp[t&1] (R11 math, dy rolled)
        const unsigned* cb = xp[t & 1];
        h2 e01[3][8], e23[3][8];
        #pragma unroll
        for (int c = 0; c < 3; ++c)
            #pragma unroll
            for (int f = 0; f < 8; ++f) { e01[c][f] = u2h(INF2); e23[c][f] = u2h(INF2); }

        #pragma unroll 1
        for (int dy = 0; dy < 5; ++dy) {
            unsigned a[3][4], mis[3][3];
            #pragma unroll
            for (int c = 0; c < 3; ++c) {
                const unsigned* xr = &cb[c*PST + (hrow + dy)*RST + (w0 >> 1)];
                uint2 u0 = *reinterpret_cast<const uint2*>(xr);
                uint2 u1 = *reinterpret_cast<const uint2*>(xr + 2);
                a[c][0] = u0.x; a[c][1] = u0.y; a[c][2] = u1.x; a[c][3] = u1.y;
                mis[c][0] = __builtin_amdgcn_alignbit(a[c][1], a[c][0], 16);
                mis[c][1] = __builtin_amdgcn_alignbit(a[c][2], a[c][1], 16);
                mis[c][2] = __builtin_amdgcn_alignbit(a[c][3], a[c][2], 16);
            }
            #pragma unroll
            for (int dx = 0; dx < 5; ++dx) {
                #pragma unroll
                for (int c = 0; c < 3; ++c) {
                    h2 p01 = u2h((dx & 1) ? mis[c][dx >> 1]     : a[c][dx >> 1]);
                    h2 p23 = u2h((dx & 1) ? mis[c][(dx >> 1)+1] : a[c][(dx >> 1)+1]);
                    const uint4* kk = reinterpret_cast<const uint4*>(
                        &kd[(dy*5 + dx)*24 + c*8]);
                    uint4 k0 = kk[0], k1 = kk[1];   // broadcast, conflict-free
                    const unsigned kf[8] = { k0.x,k0.y,k0.z,k0.w,
                                             k1.x,k1.y,k1.z,k1.w };
                    #pragma unroll
                    for (int f = 0; f < 8; ++f) {
                        e01[c][f] = __builtin_elementwise_min(e01[c][f], p01 - u2h(kf[f]));
                        e23[c][f] = __builtin_elementwise_min(e23[c][f], p23 - u2h(kf[f]));
                    }
                }
            }
        }

        // ---- store tile t (fire-and-forget; overlaps next tile's compute)
        float o0[8], o1[8], o2[8], o3[8];
        #pragma unroll
        for (int f = 0; f < 8; ++f) {
            h2 m01 = __builtin_elementwise_max(
                         __builtin_elementwise_max(e01[0][f], e01[1][f]), e01[2][f]);
            h2 m23 = __builtin_elementwise_max(
                         __builtin_elementwise_max(e23[0][f], e23[1][f]), e23[2][f]);
            o0[f] = (float)m01[0]; o1[f] = (float)m01[1];
            o2[f] = (float)m23[0]; o3[f] = (float)m23[1];
        }
        float* op = out + ((size_t)b*65536 + (size_t)(seg*16 + t*4 + hrow)*256 + w0) * 8;
        reinterpret_cast<float4*>(op)[0] = make_float4(o0[0],o0[1],o0[2],o0[3]);
        reinterpret_cast<float4*>(op)[1] = make_float4(o0[4],o0[5],o0[6],o0[7]);
        reinterpret_cast<float4*>(op)[2] = make_float4(o1[0],o1[1],o1[2],o1[3]);
        reinterpret_cast<float4*>(op)[3] = make_float4(o1[4],o1[5],o1[6],o1[7]);
        reinterpret_cast<float4*>(op)[4] = make_float4(o2[0],o2[1],o2[2],o2[3]);
        reinterpret_cast<float4*>(op)[5] = make_float4(o2[4],o2[5],o2[6],o2[7]);
        reinterpret_cast<float4*>(op)[6] = make_float4(o3[0],o3[1],o3[2],o3[3]);
        reinterpret_cast<float4*>(op)[7] = make_float4(o3[4],o3[5],o3[6],o3[7]);

        // ---- pack next tile into the other buffer
        if (t < 3) {
            unsigned* nb = xp[(t + 1) & 1];
            #pragma unroll
            for (int k = 0; k < 2; ++k) {
                int base = (rr0 + k * 4) * RST + 2 * pg + 1;
                float4 v0 = nv[k*3], v1 = nv[k*3+1], v2 = nv[k*3+2];
                const float fv[12] = { v0.x,v0.y,v0.z,v0.w, v1.x,v1.y,v1.z,v1.w,
                                       v2.x,v2.y,v2.z,v2.w };
                #pragma unroll
                for (int c = 0; c < 3; ++c) {
                    nb[c*PST + base]     = nrv[k] ? packh(fv[c],   fv[3+c]) : INF2;
                    nb[c*PST + base + 1] = nrv[k] ? packh(fv[6+c], fv[9+c]) : INF2;
                }
            }
            if (tid < 48) {
                int c = tid >> 4, rem = tid & 15, rr = rem >> 1, side = rem & 1;
                nb[c*PST + rr*RST + (side ? 129 : 0)] = INF2;
            }
        }
        __syncthreads();
    }
}

extern "C" void kernel_launch(void* const* d_in, const int* in_sizes, int n_in,
                              void* d_out, int out_size, void* d_ws, size_t ws_size,
                              hipStream_t stream) {
    const float* x    = (const float*)d_in[0];
    const float* kern = (const float*)d_in[1];
    float* out        = (float*)d_out;
    maxero_pipe<<<512, 256, 0, stream>>>(x, kern, out);  // 32 img x 16 segments
}

// Round 17
// 52.390 us; speedup vs baseline: 1.2451x; 1.2451x over previous
//
#include <hip/hip_runtime.h>
#include <math.h>

// MaxofErosions2D, scalar-f32 + min3 fusion, SGPR k (s_load), planar-f32 LDS x.
// out[b,h,w,f] = max_c min_{dy,dx} ( x[b,h+dy-2,w+dx-2,c] - kern[4-dy,4-dx,c,f] )
// x: (32,256,256,3) f32, kern: (5,5,3,8) f32, out: (32,256,256,8) f32.
//
// R17 theory: R11's cap is the LDS pipe co-saturated with VALU (150 broadcast
// b128 k-reads/thread ~= 26us/CU vs 32us VALU, dependency-coupled -> neither
// pipe reaches 100%). Fix: k is wave-uniform -> compiler s_loads it to SGPRs
// (free VOP operand, ZERO LDS traffic); f32 math with fminf-chain -> v_min3
// fusion: 600 sub + 360 min = 1920cy/px vs pk's 2400, exact f32 (absmax 0).
// R13's failure avoided: 1 px/thread single-pass -> acc 24 + xr 15 ~= 60 VGPR.
// Geometry: 8192 blocks x 256 thr (R3's config, the only 80% VALUBusy point).
// x tile: channel-planar f32 [3][5][264] = 15.8 KB, conflict-free b32 reads.

#define Hq 256

__global__ __launch_bounds__(256) void maxero_sg(
    const float* __restrict__ x,
    const float* __restrict__ kern,
    float* __restrict__ out)
{
    __shared__ float xt[3][5][264];    // [c][tile row][col+2], cols -2..261

    const int tid = threadIdx.x;       // = output col w
    const int bI  = blockIdx.x;        // 8192 blocks
    const int b   = bI >> 8;           // image 0..31
    const int h   = bI & 255;          // output row

    const float INF = __builtin_inff();
    const float* xb = x + (size_t)b * (Hq * 256 * 3);

    // ---- stage 5 rows (h-2..h+2), planar; row-clamp + inf for OOB rows
    #pragma unroll
    for (int r = 0; r < 5; ++r) {
        int rr  = h - 2 + r;
        bool rv = (unsigned)rr < 256u;
        int rc  = min(max(rr, 0), 255);
        const float* p = xb + rc * 768 + tid * 3;   // dwordx3, contiguous/wave
        float v0 = p[0], v1 = p[1], v2 = p[2];
        xt[0][r][tid + 2] = rv ? v0 : INF;
        xt[1][r][tid + 2] = rv ? v1 : INF;
        xt[2][r][tid + 2] = rv ? v2 : INF;
    }
    // halo cols: idx {0,1} (cols -2,-1) and {258,259} (cols 256,257), 15 (c,r)
    if (tid < 60) {
        int cr = tid >> 2;             // 0..14
        int c  = cr / 5, r = cr - 5 * c;
        int q  = tid & 3;
        int idx = (q < 2) ? q : 256 + q;   // 0,1,258,259
        xt[c][r][idx] = INF;
    }
    __syncthreads();

    float acc[3][8];
    #pragma unroll
    for (int c = 0; c < 3; ++c)
        #pragma unroll
        for (int f = 0; f < 8; ++f)
            acc[c][f] = INF;

    #pragma unroll
    for (int dy = 0; dy < 5; ++dy) {
        // 5 window cols x 3 ch, conflict-free b32 (consecutive lanes/addrs)
        float xr[3][5];
        #pragma unroll
        for (int c = 0; c < 3; ++c)
            #pragma unroll
            for (int j = 0; j < 5; ++j)
                xr[c][j] = xt[c][dy][tid + j];

        #pragma unroll
        for (int c = 0; c < 3; ++c) {
            #pragma unroll
            for (int f = 0; f < 8; ++f) {
                // wave-uniform taps -> s_load -> SGPR operands (free, no LDS)
                float k0 = kern[((4 - dy) * 5 + 4) * 24 + c * 8 + f];  // dx=0
                float k1 = kern[((4 - dy) * 5 + 3) * 24 + c * 8 + f];
                float k2 = kern[((4 - dy) * 5 + 2) * 24 + c * 8 + f];
                float k3 = kern[((4 - dy) * 5 + 1) * 24 + c * 8 + f];
                float k4 = kern[((4 - dy) * 5 + 0) * 24 + c * 8 + f];
                float a  = acc[c][f];
                a = fminf(fminf(a, xr[c][0] - k0), xr[c][1] - k1);  // v_min3
                a = fminf(fminf(a, xr[c][2] - k2), xr[c][3] - k3);  // v_min3
                acc[c][f] = fminf(a, xr[c][4] - k4);
            }
        }
    }

    // ---- epilogue: channel max (v_max3), 2x dwordx4 store (32B/lane stride)
    float4 oA, oB;
    oA.x = fmaxf(fmaxf(acc[0][0], acc[1][0]), acc[2][0]);
    oA.y = fmaxf(fmaxf(acc[0][1], acc[1][1]), acc[2][1]);
    oA.z = fmaxf(fmaxf(acc[0][2], acc[1][2]), acc[2][2]);
    oA.w = fmaxf(fmaxf(acc[0][3], acc[1][3]), acc[2][3]);
    oB.x = fmaxf(fmaxf(acc[0][4], acc[1][4]), acc[2][4]);
    oB.y = fmaxf(fmaxf(acc[0][5], acc[1][5]), acc[2][5]);
    oB.z = fmaxf(fmaxf(acc[0][6], acc[1][6]), acc[2][6]);
    oB.w = fmaxf(fmaxf(acc[0][7], acc[1][7]), acc[2][7]);

    float* op = out + ((size_t)b * 65536 + (size_t)h * 256 + tid) * 8;
    reinterpret_cast<float4*>(op)[0] = oA;
    reinterpret_cast<float4*>(op)[1] = oB;
}

extern "C" void kernel_launch(void* const* d_in, const int* in_sizes, int n_in,
                              void* d_out, int out_size, void* d_ws, size_t ws_size,
                              hipStream_t stream) {
    const float* x    = (const float*)d_in[0];
    const float* kern = (const float*)d_in[1];
    float* out        = (float*)d_out;
    maxero_sg<<<8192, 256, 0, stream>>>(x, kern, out);  // 32 img x 256 rows
}